// Round 1
// baseline (563.757 us; speedup 1.0000x reference)
//
#include <hip/hip_runtime.h>

// AirMPNN: 3 rounds of air_conv + head MLP.
// Key transform: mlp1(sigmoid) depends only on the SOURCE NODE, so compute
// p[n] = sigmoid(mlp1(xc[n])) per node (100k) instead of per edge (3.2M),
// then the edge phase is just agg[dst] += p[src] * eattr  (scatter-add).

__device__ __forceinline__ void load_smem(float* dstp, const float* __restrict__ srcp,
                                          int n, int tid, int nthreads) {
    for (int i = tid; i < n; i += nthreads) dstp[i] = srcp[i];
}

// sigmoid(mlp1(xj)): 9 -> 32 relu -> 32 relu -> 1 sigmoid
__device__ __forceinline__ float mlp1_eval(const float* xj,
    const float* sW1, const float* sb1, const float* sW2, const float* sb2,
    const float* sW3, float sb3)
{
    float h1[32];
#pragma unroll
    for (int j = 0; j < 32; ++j) h1[j] = sb1[j];
#pragma unroll
    for (int i = 0; i < 9; ++i) {
        float v = xj[i];
#pragma unroll
        for (int j = 0; j < 32; ++j) h1[j] = fmaf(v, sW1[i*32+j], h1[j]);
    }
#pragma unroll
    for (int j = 0; j < 32; ++j) h1[j] = fmaxf(h1[j], 0.0f);
    float h2[32];
#pragma unroll
    for (int j = 0; j < 32; ++j) h2[j] = sb2[j];
#pragma unroll
    for (int i = 0; i < 32; ++i) {
        float v = h1[i];
#pragma unroll
        for (int j = 0; j < 32; ++j) h2[j] = fmaf(v, sW2[i*32+j], h2[j]);
    }
    float m = sb3;
#pragma unroll
    for (int i = 0; i < 32; ++i) m = fmaf(fmaxf(h2[i], 0.0f), sW3[i], m);
    return 1.0f / (1.0f + __expf(-m));
}

// p0: p[n] = sigmoid(mlp1(x[n])) for the initial features; also zero agg[3N].
__global__ __launch_bounds__(256) void p0_kernel(
    const float* __restrict__ x,
    const float* __restrict__ W1, const float* __restrict__ b1,
    const float* __restrict__ W2, const float* __restrict__ b2,
    const float* __restrict__ W3, const float* __restrict__ b3,
    float* __restrict__ p, float* __restrict__ agg3, int N)
{
    __shared__ float sW1[288], sb1[32], sW2[1024], sb2[32], sW3[32], sb3s[1];
    int tid = threadIdx.x;
    load_smem(sW1, W1, 288, tid, 256);
    load_smem(sb1, b1, 32, tid, 256);
    load_smem(sW2, W2, 1024, tid, 256);
    load_smem(sb2, b2, 32, tid, 256);
    load_smem(sW3, W3, 32, tid, 256);
    if (tid == 0) sb3s[0] = b3[0];
    __syncthreads();
    int n = blockIdx.x * 256 + tid;
    if (n >= N) return;
    agg3[n] = 0.0f; agg3[N + n] = 0.0f; agg3[2*N + n] = 0.0f;
    float xj[9];
#pragma unroll
    for (int i = 0; i < 9; ++i) xj[i] = x[(size_t)n*9 + i];
    p[n] = mlp1_eval(xj, sW1, sb1, sW2, sb2, sW3, sb3s[0]);
}

// scatter: agg[dst[e]] += p[src[e]] * eattr[e], 4 edges per thread
__global__ __launch_bounds__(256) void scatter_kernel4(
    const float* __restrict__ p, const int* __restrict__ src, const int* __restrict__ dst,
    const float* __restrict__ eattr, float* __restrict__ agg, int E)
{
    int i = (blockIdx.x * 256 + threadIdx.x) * 4;
    if (i + 3 < E) {
        int4   s = *(const int4*)(src + i);
        int4   d = *(const int4*)(dst + i);
        float4 a = *(const float4*)(eattr + i);
        atomicAdd(&agg[d.x], p[s.x] * a.x);
        atomicAdd(&agg[d.y], p[s.y] * a.y);
        atomicAdd(&agg[d.z], p[s.z] * a.z);
        atomicAdd(&agg[d.w], p[s.w] * a.w);
    } else {
        for (; i < E; ++i) atomicAdd(&agg[dst[i]], p[src[i]] * eattr[i]);
    }
}

__global__ __launch_bounds__(256) void scatter_kernel1(
    const float* __restrict__ p, const int* __restrict__ src, const int* __restrict__ dst,
    const float* __restrict__ eattr, float* __restrict__ agg, int E)
{
    int i = blockIdx.x * 256 + threadIdx.x;
    if (i < E) atomicAdd(&agg[dst[i]], p[src[i]] * eattr[i]);
}

// node: t=[xc, agg] -> mlp2 -> comb; then either (xout, p_next) or final head
template<bool LAST>
__global__ __launch_bounds__(256) void node_kernel(
    const float* __restrict__ xin, const float* __restrict__ agg,
    const float* __restrict__ V1, const float* __restrict__ c1,
    const float* __restrict__ V2, const float* __restrict__ c2,
    const float* __restrict__ W1, const float* __restrict__ b1,
    const float* __restrict__ W2, const float* __restrict__ b2,
    const float* __restrict__ W3, const float* __restrict__ b3,
    const float* __restrict__ H1, const float* __restrict__ d1,
    const float* __restrict__ H2, const float* __restrict__ d2,
    float* __restrict__ xout, float* __restrict__ pout,
    float* __restrict__ finalout, int N)
{
    __shared__ float sV1[160], sc1[16], sV2[128], sc2[8];
    __shared__ float sW1[288], sb1[32], sW2[1024], sb2[32], sW3[32], sb3s[1];
    __shared__ float sH1[128], sd1[16], sH2[16], sd2s[1];
    int tid = threadIdx.x;
    load_smem(sV1, V1, 160, tid, 256);
    load_smem(sc1, c1, 16, tid, 256);
    load_smem(sV2, V2, 128, tid, 256);
    load_smem(sc2, c2, 8, tid, 256);
    if (!LAST) {
        load_smem(sW1, W1, 288, tid, 256);
        load_smem(sb1, b1, 32, tid, 256);
        load_smem(sW2, W2, 1024, tid, 256);
        load_smem(sb2, b2, 32, tid, 256);
        load_smem(sW3, W3, 32, tid, 256);
        if (tid == 0) sb3s[0] = b3[0];
    } else {
        load_smem(sH1, H1, 128, tid, 256);
        load_smem(sd1, d1, 16, tid, 256);
        load_smem(sH2, H2, 16, tid, 256);
        if (tid == 0) sd2s[0] = d2[0];
    }
    __syncthreads();
    int n = blockIdx.x * 256 + tid;
    if (n >= N) return;

    float t[10];
#pragma unroll
    for (int i = 0; i < 9; ++i) t[i] = xin[(size_t)n*9 + i];
    t[9] = agg[n];

    float u[16];
#pragma unroll
    for (int j = 0; j < 16; ++j) u[j] = sc1[j];
#pragma unroll
    for (int i = 0; i < 10; ++i) {
        float v = t[i];
#pragma unroll
        for (int j = 0; j < 16; ++j) u[j] = fmaf(v, sV1[i*16+j], u[j]);
    }
#pragma unroll
    for (int j = 0; j < 16; ++j) u[j] = fmaxf(u[j], 0.0f);

    float comb[8];
#pragma unroll
    for (int j = 0; j < 8; ++j) comb[j] = sc2[j];
#pragma unroll
    for (int i = 0; i < 16; ++i) {
        float v = u[i];
#pragma unroll
        for (int j = 0; j < 8; ++j) comb[j] = fmaf(v, sV2[i*8+j], comb[j]);
    }
#pragma unroll
    for (int j = 0; j < 8; ++j) comb[j] = fmaxf(comb[j], 0.0f);

    if (!LAST) {
        float xnew[9];
        xnew[0] = t[0];
#pragma unroll
        for (int j = 0; j < 8; ++j) xnew[1+j] = comb[j];
#pragma unroll
        for (int i = 0; i < 9; ++i) xout[(size_t)n*9 + i] = xnew[i];
        pout[n] = mlp1_eval(xnew, sW1, sb1, sW2, sb2, sW3, sb3s[0]);
    } else {
        float hh[16];
#pragma unroll
        for (int j = 0; j < 16; ++j) hh[j] = sd1[j];
#pragma unroll
        for (int i = 0; i < 8; ++i) {
            float v = comb[i];
#pragma unroll
            for (int j = 0; j < 16; ++j) hh[j] = fmaf(v, sH1[i*16+j], hh[j]);
        }
        float o = sd2s[0];
#pragma unroll
        for (int j = 0; j < 16; ++j) o = fmaf(fmaxf(hh[j], 0.0f), sH2[j], o);
        finalout[n] = 1.0f / (1.0f + __expf(-o));
    }
}

extern "C" void kernel_launch(void* const* d_in, const int* in_sizes, int n_in,
                              void* d_out, int out_size, void* d_ws, size_t ws_size,
                              hipStream_t stream)
{
    const float* x     = (const float*)d_in[0];
    const float* eattr = (const float*)d_in[1];
    const int*   eidx  = (const int*)d_in[2];
    const float *W1=(const float*)d_in[3],  *b1=(const float*)d_in[4];
    const float *W2=(const float*)d_in[5],  *b2=(const float*)d_in[6];
    const float *W3=(const float*)d_in[7],  *b3=(const float*)d_in[8];
    const float *V1=(const float*)d_in[9],  *c1=(const float*)d_in[10];
    const float *V2=(const float*)d_in[11], *c2=(const float*)d_in[12];
    const float *H1=(const float*)d_in[13], *d1=(const float*)d_in[14];
    const float *H2=(const float*)d_in[15], *d2=(const float*)d_in[16];
    int N = in_sizes[0] / 9;
    int E = in_sizes[1];
    const int* src = eidx;
    const int* dst = eidx + E;
    float* out = (float*)d_out;

    float* ws   = (float*)d_ws;
    float* xcA  = ws;                       // N*9
    float* xcB  = xcA + (size_t)N * 9;      // N*9
    float* p    = xcB + (size_t)N * 9;      // N
    float* agg3 = p + N;                    // 3*N

    dim3 thr(256);
    dim3 blkN((N + 255) / 256);
    dim3 blkE4(((E + 3) / 4 + 255) / 256);
    dim3 blkE1((E + 255) / 256);

    p0_kernel<<<blkN, thr, 0, stream>>>(x, W1, b1, W2, b2, W3, b3, p, agg3, N);

    // round 1: x -> xcA
    if ((E & 3) == 0)
        scatter_kernel4<<<blkE4, thr, 0, stream>>>(p, src, dst, eattr, agg3, E);
    else
        scatter_kernel1<<<blkE1, thr, 0, stream>>>(p, src, dst, eattr, agg3, E);
    node_kernel<false><<<blkN, thr, 0, stream>>>(x, agg3, V1,c1,V2,c2, W1,b1,W2,b2,W3,b3,
                                                 H1,d1,H2,d2, xcA, p, nullptr, N);
    // round 2: xcA -> xcB
    if ((E & 3) == 0)
        scatter_kernel4<<<blkE4, thr, 0, stream>>>(p, src, dst, eattr, agg3 + N, E);
    else
        scatter_kernel1<<<blkE1, thr, 0, stream>>>(p, src, dst, eattr, agg3 + N, E);
    node_kernel<false><<<blkN, thr, 0, stream>>>(xcA, agg3 + N, V1,c1,V2,c2, W1,b1,W2,b2,W3,b3,
                                                 H1,d1,H2,d2, xcB, p, nullptr, N);
    // round 3: xcB -> final head
    if ((E & 3) == 0)
        scatter_kernel4<<<blkE4, thr, 0, stream>>>(p, src, dst, eattr, agg3 + 2*(size_t)N, E);
    else
        scatter_kernel1<<<blkE1, thr, 0, stream>>>(p, src, dst, eattr, agg3 + 2*(size_t)N, E);
    node_kernel<true><<<blkN, thr, 0, stream>>>(xcB, agg3 + 2*(size_t)N, V1,c1,V2,c2, W1,b1,W2,b2,W3,b3,
                                                H1,d1,H2,d2, nullptr, nullptr, out, N);
}

// Round 2
// 229.943 us; speedup vs baseline: 2.4517x; 2.4517x over previous
//
#include <hip/hip_runtime.h>

typedef unsigned int uint;
typedef unsigned char uchar;

// Bucketed-CSR AirMPNN.
// Phase 1 (once per call): counting-sort edges by dst-bucket (dst>>7) with
//   zero global atomics (LDS histograms + hierarchical scan).
// Phase 2 (x3 rounds): per-bucket block aggregates msg into LDS (ds_add_f32),
//   then computes the node MLP for its 128 nodes directly from LDS.
// p[n] = sigmoid(mlp1(xc[n])) is per-NODE (mlp1 depends only on source node).

#define NPB 128        // nodes per bucket
#define NPB_SHIFT 7
#define MAXB 1024      // max buckets (N <= 131072)
#define NBLK 640       // histogram/scatter blocks

__device__ __forceinline__ void load_smem(float* dstp, const float* __restrict__ srcp,
                                          int n, int tid, int nthreads) {
    for (int i = tid; i < n; i += nthreads) dstp[i] = srcp[i];
}

// sigmoid(mlp1(xj)): 9 -> 32 relu -> 32 relu -> 1 sigmoid
__device__ __forceinline__ float mlp1_eval(const float* xj,
    const float* sW1, const float* sb1, const float* sW2, const float* sb2,
    const float* sW3, float sb3)
{
    float h1[32];
#pragma unroll
    for (int j = 0; j < 32; ++j) h1[j] = sb1[j];
#pragma unroll
    for (int i = 0; i < 9; ++i) {
        float v = xj[i];
#pragma unroll
        for (int j = 0; j < 32; ++j) h1[j] = fmaf(v, sW1[i*32+j], h1[j]);
    }
#pragma unroll
    for (int j = 0; j < 32; ++j) h1[j] = fmaxf(h1[j], 0.0f);
    float h2[32];
#pragma unroll
    for (int j = 0; j < 32; ++j) h2[j] = sb2[j];
#pragma unroll
    for (int i = 0; i < 32; ++i) {
        float v = h1[i];
#pragma unroll
        for (int j = 0; j < 32; ++j) h2[j] = fmaf(v, sW2[i*32+j], h2[j]);
    }
    float m = sb3;
#pragma unroll
    for (int i = 0; i < 32; ++i) m = fmaf(fmaxf(h2[i], 0.0f), sW3[i], m);
    return 1.0f / (1.0f + __expf(-m));
}

// p0: p[n] = sigmoid(mlp1(x[n])); optionally zero agg3 (fallback path)
__global__ __launch_bounds__(256) void p0_kernel(
    const float* __restrict__ x,
    const float* __restrict__ W1, const float* __restrict__ b1,
    const float* __restrict__ W2, const float* __restrict__ b2,
    const float* __restrict__ W3, const float* __restrict__ b3,
    float* __restrict__ p, float* __restrict__ agg3, int N)
{
    __shared__ float sW1[288], sb1[32], sW2[1024], sb2[32], sW3[32], sb3s[1];
    int tid = threadIdx.x;
    load_smem(sW1, W1, 288, tid, 256);
    load_smem(sb1, b1, 32, tid, 256);
    load_smem(sW2, W2, 1024, tid, 256);
    load_smem(sb2, b2, 32, tid, 256);
    load_smem(sW3, W3, 32, tid, 256);
    if (tid == 0) sb3s[0] = b3[0];
    __syncthreads();
    int n = blockIdx.x * 256 + tid;
    if (n >= N) return;
    if (agg3) { agg3[n] = 0.0f; agg3[N + n] = 0.0f; agg3[2*(size_t)N + n] = 0.0f; }
    float xj[9];
#pragma unroll
    for (int i = 0; i < 9; ++i) xj[i] = x[(size_t)n*9 + i];
    p[n] = mlp1_eval(xj, sW1, sb1, sW2, sb2, sW3, sb3s[0]);
}

// ---- bucket sort (no global atomics) ----

__global__ __launch_bounds__(256) void hist_kernel(
    const int* __restrict__ dst, uint* __restrict__ hist_g, int E, int chunk, int B)
{
    __shared__ uint hist[MAXB];
    int tid = threadIdx.x;
    for (int i = tid; i < MAXB; i += 256) hist[i] = 0u;
    __syncthreads();
    int start = blockIdx.x * chunk;
    int end = min(E, start + chunk);
    for (int e = start + tid; e < end; e += 256)
        atomicAdd(&hist[((uint)dst[e]) >> NPB_SHIFT], 1u);
    __syncthreads();
    for (int b = tid; b < B; b += 256)
        hist_g[(size_t)b * NBLK + blockIdx.x] = hist[b];
}

// per-bin exclusive scan over the NBLK block-counts; total[bin] = bin sum
__global__ __launch_bounds__(1024) void scanA_kernel(
    uint* __restrict__ hist_g, uint* __restrict__ total)
{
    __shared__ uint s[1024];
    int t = threadIdx.x;
    int b = blockIdx.x;
    uint v = (t < NBLK) ? hist_g[(size_t)b * NBLK + t] : 0u;
    s[t] = v;
    __syncthreads();
    for (int off = 1; off < 1024; off <<= 1) {
        uint xv = (t >= off) ? s[t - off] : 0u;
        __syncthreads();
        s[t] += xv;
        __syncthreads();
    }
    if (t < NBLK) hist_g[(size_t)b * NBLK + t] = s[t] - v;  // exclusive
    if (t == NBLK - 1) total[b] = s[t];
}

// exclusive scan of bin totals -> base[b]; base[B] = E
__global__ __launch_bounds__(1024) void scanB_kernel(
    const uint* __restrict__ total, uint* __restrict__ base, int B)
{
    __shared__ uint s[1024];
    int t = threadIdx.x;
    uint v = (t < B) ? total[t] : 0u;
    s[t] = v;
    __syncthreads();
    for (int off = 1; off < 1024; off <<= 1) {
        uint xv = (t >= off) ? s[t - off] : 0u;
        __syncthreads();
        s[t] += xv;
        __syncthreads();
    }
    if (t < B) base[t] = s[t] - v;
    if (t == B - 1) base[B] = s[t];
}

// scatter edges into bucket-sorted arrays: ia=(src, eattr bits), dloc = dst&127
__global__ __launch_bounds__(256) void scatter_sort_kernel(
    const int* __restrict__ dst, const int* __restrict__ src,
    const float* __restrict__ ea, const uint* __restrict__ base,
    const uint* __restrict__ hist_g,
    int2* __restrict__ ia, uchar* __restrict__ dloc, int E, int chunk, int B)
{
    __shared__ uint cnt[MAXB];
    int tid = threadIdx.x;
    for (int b = tid; b < B; b += 256)
        cnt[b] = base[b] + hist_g[(size_t)b * NBLK + blockIdx.x];
    __syncthreads();
    int start = blockIdx.x * chunk;
    int end = min(E, start + chunk);
    for (int e = start + tid; e < end; e += 256) {
        int d = dst[e];
        uint bin = ((uint)d) >> NPB_SHIFT;
        uint pos = atomicAdd(&cnt[bin], 1u);   // LDS atomic (cheap)
        int2 v; v.x = src[e]; v.y = __float_as_int(ea[e]);
        ia[pos] = v;
        dloc[pos] = (uchar)(d & (NPB - 1));
    }
}

// ---- fused aggregate + node MLP per bucket ----
template<bool LAST>
__global__ __launch_bounds__(256) void aggnode_kernel(
    const float* __restrict__ xin,
    const int2* __restrict__ ia, const uchar* __restrict__ dloc,
    const uint* __restrict__ base, const float* __restrict__ p_in,
    const float* __restrict__ V1, const float* __restrict__ c1,
    const float* __restrict__ V2, const float* __restrict__ c2,
    const float* __restrict__ W1, const float* __restrict__ b1,
    const float* __restrict__ W2, const float* __restrict__ b2,
    const float* __restrict__ W3, const float* __restrict__ b3,
    const float* __restrict__ H1, const float* __restrict__ d1,
    const float* __restrict__ H2, const float* __restrict__ d2,
    float* __restrict__ xout, float* __restrict__ pout,
    float* __restrict__ finalout, int N)
{
    __shared__ float aggl[NPB];
    __shared__ float sV1[160], sc1[16], sV2[128], sc2[8];
    __shared__ float sW1[288], sb1[32], sW2[1024], sb2[32], sW3[32], sbx[1];
    __shared__ float sH1[128], sd1[16], sH2[16], sdx[1];
    int tid = threadIdx.x;
    for (int i = tid; i < NPB; i += 256) aggl[i] = 0.0f;
    load_smem(sV1, V1, 160, tid, 256);
    load_smem(sc1, c1, 16, tid, 256);
    load_smem(sV2, V2, 128, tid, 256);
    load_smem(sc2, c2, 8, tid, 256);
    if (!LAST) {
        load_smem(sW1, W1, 288, tid, 256);
        load_smem(sb1, b1, 32, tid, 256);
        load_smem(sW2, W2, 1024, tid, 256);
        load_smem(sb2, b2, 32, tid, 256);
        load_smem(sW3, W3, 32, tid, 256);
        if (tid == 0) sbx[0] = b3[0];
    } else {
        load_smem(sH1, H1, 128, tid, 256);
        load_smem(sd1, d1, 16, tid, 256);
        load_smem(sH2, H2, 16, tid, 256);
        if (tid == 0) sdx[0] = d2[0];
    }
    __syncthreads();

    int b = blockIdx.x;
    uint e0 = base[b], e1 = base[b + 1];
    for (uint e = e0 + tid; e < e1; e += 256) {
        int2 v = ia[e];
        atomicAdd(&aggl[dloc[e]], p_in[v.x] * __int_as_float(v.y));  // ds_add_f32
    }
    __syncthreads();

    int n = b * NPB + tid;
    if (tid >= NPB || n >= N) return;

    float t[10];
#pragma unroll
    for (int i = 0; i < 9; ++i) t[i] = xin[(size_t)n*9 + i];
    t[9] = aggl[tid];   // (agg - 0)/1

    float u[16];
#pragma unroll
    for (int j = 0; j < 16; ++j) u[j] = sc1[j];
#pragma unroll
    for (int i = 0; i < 10; ++i) {
        float v = t[i];
#pragma unroll
        for (int j = 0; j < 16; ++j) u[j] = fmaf(v, sV1[i*16+j], u[j]);
    }
#pragma unroll
    for (int j = 0; j < 16; ++j) u[j] = fmaxf(u[j], 0.0f);

    float comb[8];
#pragma unroll
    for (int j = 0; j < 8; ++j) comb[j] = sc2[j];
#pragma unroll
    for (int i = 0; i < 16; ++i) {
        float v = u[i];
#pragma unroll
        for (int j = 0; j < 8; ++j) comb[j] = fmaf(v, sV2[i*8+j], comb[j]);
    }
#pragma unroll
    for (int j = 0; j < 8; ++j) comb[j] = fmaxf(comb[j], 0.0f);

    if (!LAST) {
        float xnew[9];
        xnew[0] = t[0];
#pragma unroll
        for (int j = 0; j < 8; ++j) xnew[1+j] = comb[j];
#pragma unroll
        for (int i = 0; i < 9; ++i) xout[(size_t)n*9 + i] = xnew[i];
        pout[n] = mlp1_eval(xnew, sW1, sb1, sW2, sb2, sW3, sbx[0]);
    } else {
        float hh[16];
#pragma unroll
        for (int j = 0; j < 16; ++j) hh[j] = sd1[j];
#pragma unroll
        for (int i = 0; i < 8; ++i) {
            float v = comb[i];
#pragma unroll
            for (int j = 0; j < 16; ++j) hh[j] = fmaf(v, sH1[i*16+j], hh[j]);
        }
        float o = sdx[0];
#pragma unroll
        for (int j = 0; j < 16; ++j) o = fmaf(fmaxf(hh[j], 0.0f), sH2[j], o);
        finalout[n] = 1.0f / (1.0f + __expf(-o));
    }
}

// ---- fallback (R1 atomic path) kernels ----

__global__ __launch_bounds__(256) void scatter_kernel4(
    const float* __restrict__ p, const int* __restrict__ src, const int* __restrict__ dst,
    const float* __restrict__ eattr, float* __restrict__ agg, int E)
{
    int i = (blockIdx.x * 256 + threadIdx.x) * 4;
    if (i + 3 < E) {
        int4   s = *(const int4*)(src + i);
        int4   d = *(const int4*)(dst + i);
        float4 a = *(const float4*)(eattr + i);
        atomicAdd(&agg[d.x], p[s.x] * a.x);
        atomicAdd(&agg[d.y], p[s.y] * a.y);
        atomicAdd(&agg[d.z], p[s.z] * a.z);
        atomicAdd(&agg[d.w], p[s.w] * a.w);
    } else {
        for (; i < E; ++i) atomicAdd(&agg[dst[i]], p[src[i]] * eattr[i]);
    }
}

template<bool LAST>
__global__ __launch_bounds__(256) void node_kernel(
    const float* __restrict__ xin, const float* __restrict__ agg,
    const float* __restrict__ V1, const float* __restrict__ c1,
    const float* __restrict__ V2, const float* __restrict__ c2,
    const float* __restrict__ W1, const float* __restrict__ b1,
    const float* __restrict__ W2, const float* __restrict__ b2,
    const float* __restrict__ W3, const float* __restrict__ b3,
    const float* __restrict__ H1, const float* __restrict__ d1,
    const float* __restrict__ H2, const float* __restrict__ d2,
    float* __restrict__ xout, float* __restrict__ pout,
    float* __restrict__ finalout, int N)
{
    __shared__ float sV1[160], sc1[16], sV2[128], sc2[8];
    __shared__ float sW1[288], sb1[32], sW2[1024], sb2[32], sW3[32], sbx[1];
    __shared__ float sH1[128], sd1[16], sH2[16], sdx[1];
    int tid = threadIdx.x;
    load_smem(sV1, V1, 160, tid, 256);
    load_smem(sc1, c1, 16, tid, 256);
    load_smem(sV2, V2, 128, tid, 256);
    load_smem(sc2, c2, 8, tid, 256);
    if (!LAST) {
        load_smem(sW1, W1, 288, tid, 256);
        load_smem(sb1, b1, 32, tid, 256);
        load_smem(sW2, W2, 1024, tid, 256);
        load_smem(sb2, b2, 32, tid, 256);
        load_smem(sW3, W3, 32, tid, 256);
        if (tid == 0) sbx[0] = b3[0];
    } else {
        load_smem(sH1, H1, 128, tid, 256);
        load_smem(sd1, d1, 16, tid, 256);
        load_smem(sH2, H2, 16, tid, 256);
        if (tid == 0) sdx[0] = d2[0];
    }
    __syncthreads();
    int n = blockIdx.x * 256 + tid;
    if (n >= N) return;

    float t[10];
#pragma unroll
    for (int i = 0; i < 9; ++i) t[i] = xin[(size_t)n*9 + i];
    t[9] = agg[n];

    float u[16];
#pragma unroll
    for (int j = 0; j < 16; ++j) u[j] = sc1[j];
#pragma unroll
    for (int i = 0; i < 10; ++i) {
        float v = t[i];
#pragma unroll
        for (int j = 0; j < 16; ++j) u[j] = fmaf(v, sV1[i*16+j], u[j]);
    }
#pragma unroll
    for (int j = 0; j < 16; ++j) u[j] = fmaxf(u[j], 0.0f);

    float comb[8];
#pragma unroll
    for (int j = 0; j < 8; ++j) comb[j] = sc2[j];
#pragma unroll
    for (int i = 0; i < 16; ++i) {
        float v = u[i];
#pragma unroll
        for (int j = 0; j < 8; ++j) comb[j] = fmaf(v, sV2[i*8+j], comb[j]);
    }
#pragma unroll
    for (int j = 0; j < 8; ++j) comb[j] = fmaxf(comb[j], 0.0f);

    if (!LAST) {
        float xnew[9];
        xnew[0] = t[0];
#pragma unroll
        for (int j = 0; j < 8; ++j) xnew[1+j] = comb[j];
#pragma unroll
        for (int i = 0; i < 9; ++i) xout[(size_t)n*9 + i] = xnew[i];
        pout[n] = mlp1_eval(xnew, sW1, sb1, sW2, sb2, sW3, sbx[0]);
    } else {
        float hh[16];
#pragma unroll
        for (int j = 0; j < 16; ++j) hh[j] = sd1[j];
#pragma unroll
        for (int i = 0; i < 8; ++i) {
            float v = comb[i];
#pragma unroll
            for (int j = 0; j < 16; ++j) hh[j] = fmaf(v, sH1[i*16+j], hh[j]);
        }
        float o = sdx[0];
#pragma unroll
        for (int j = 0; j < 16; ++j) o = fmaf(fmaxf(hh[j], 0.0f), sH2[j], o);
        finalout[n] = 1.0f / (1.0f + __expf(-o));
    }
}

extern "C" void kernel_launch(void* const* d_in, const int* in_sizes, int n_in,
                              void* d_out, int out_size, void* d_ws, size_t ws_size,
                              hipStream_t stream)
{
    const float* x     = (const float*)d_in[0];
    const float* eattr = (const float*)d_in[1];
    const int*   eidx  = (const int*)d_in[2];
    const float *W1=(const float*)d_in[3],  *b1=(const float*)d_in[4];
    const float *W2=(const float*)d_in[5],  *b2=(const float*)d_in[6];
    const float *W3=(const float*)d_in[7],  *b3=(const float*)d_in[8];
    const float *V1=(const float*)d_in[9],  *c1=(const float*)d_in[10];
    const float *V2=(const float*)d_in[11], *c2=(const float*)d_in[12];
    const float *H1=(const float*)d_in[13], *d1=(const float*)d_in[14];
    const float *H2=(const float*)d_in[15], *d2=(const float*)d_in[16];
    int N = in_sizes[0] / 9;
    int E = in_sizes[1];
    const int* src = eidx;
    const int* dst = eidx + E;
    float* out = (float*)d_out;
    int B = (N + NPB - 1) / NPB;

    // main-path workspace
    size_t need = (size_t)E * 8                      // ia
                + (size_t)N * 9 * 4 * 2              // xcA, xcB
                + (size_t)N * 4 * 2                  // pA, pB
                + (size_t)MAXB * NBLK * 4            // hist_g
                + (size_t)MAXB * 4                   // total
                + (size_t)(MAXB + 1) * 4             // base
                + (size_t)E                          // dloc
                + 64;

    dim3 thr(256);
    dim3 blkN((N + 255) / 256);

    if (B <= MAXB && ws_size >= need) {
        char* w = (char*)d_ws;
        int2* ia      = (int2*)w;              w += (size_t)E * 8;
        float* xcA    = (float*)w;             w += (size_t)N * 9 * 4;
        float* xcB    = (float*)w;             w += (size_t)N * 9 * 4;
        float* pA     = (float*)w;             w += (size_t)N * 4;
        float* pB     = (float*)w;             w += (size_t)N * 4;
        uint* hist_g  = (uint*)w;              w += (size_t)MAXB * NBLK * 4;
        uint* total   = (uint*)w;              w += (size_t)MAXB * 4;
        uint* base    = (uint*)w;              w += (size_t)(MAXB + 1) * 4;
        uchar* dloc   = (uchar*)w;

        int chunk = (E + NBLK - 1) / NBLK;

        p0_kernel<<<blkN, thr, 0, stream>>>(x, W1,b1,W2,b2,W3,b3, pA, nullptr, N);
        hist_kernel<<<dim3(NBLK), thr, 0, stream>>>(dst, hist_g, E, chunk, B);
        scanA_kernel<<<dim3(B), dim3(1024), 0, stream>>>(hist_g, total);
        scanB_kernel<<<dim3(1), dim3(1024), 0, stream>>>(total, base, B);
        scatter_sort_kernel<<<dim3(NBLK), thr, 0, stream>>>(dst, src, eattr, base, hist_g,
                                                            ia, dloc, E, chunk, B);
        aggnode_kernel<false><<<dim3(B), thr, 0, stream>>>(x,   ia, dloc, base, pA,
            V1,c1,V2,c2, W1,b1,W2,b2,W3,b3, H1,d1,H2,d2, xcA, pB, nullptr, N);
        aggnode_kernel<false><<<dim3(B), thr, 0, stream>>>(xcA, ia, dloc, base, pB,
            V1,c1,V2,c2, W1,b1,W2,b2,W3,b3, H1,d1,H2,d2, xcB, pA, nullptr, N);
        aggnode_kernel<true><<<dim3(B), thr, 0, stream>>>(xcB, ia, dloc, base, pA,
            V1,c1,V2,c2, W1,b1,W2,b2,W3,b3, H1,d1,H2,d2, nullptr, nullptr, out, N);
    } else {
        // fallback: R1 atomic path (ws ~8.8 MB)
        float* ws   = (float*)d_ws;
        float* xcA  = ws;
        float* xcB  = xcA + (size_t)N * 9;
        float* p    = xcB + (size_t)N * 9;
        float* agg3 = p + N;
        dim3 blkE4(((E + 3) / 4 + 255) / 256);

        p0_kernel<<<blkN, thr, 0, stream>>>(x, W1,b1,W2,b2,W3,b3, p, agg3, N);
        scatter_kernel4<<<blkE4, thr, 0, stream>>>(p, src, dst, eattr, agg3, E);
        node_kernel<false><<<blkN, thr, 0, stream>>>(x, agg3, V1,c1,V2,c2, W1,b1,W2,b2,W3,b3,
                                                     H1,d1,H2,d2, xcA, p, nullptr, N);
        scatter_kernel4<<<blkE4, thr, 0, stream>>>(p, src, dst, eattr, agg3 + N, E);
        node_kernel<false><<<blkN, thr, 0, stream>>>(xcA, agg3 + N, V1,c1,V2,c2, W1,b1,W2,b2,W3,b3,
                                                     H1,d1,H2,d2, xcB, p, nullptr, N);
        scatter_kernel4<<<blkE4, thr, 0, stream>>>(p, src, dst, eattr, agg3 + 2*(size_t)N, E);
        node_kernel<true><<<blkN, thr, 0, stream>>>(xcB, agg3 + 2*(size_t)N, V1,c1,V2,c2,
                                                    W1,b1,W2,b2,W3,b3, H1,d1,H2,d2,
                                                    nullptr, nullptr, out, N);
    }
}

// Round 3
// 163.392 us; speedup vs baseline: 3.4503x; 1.4073x over previous
//
#include <hip/hip_runtime.h>

typedef unsigned int uint;
typedef unsigned char uchar;

// Bucketed-CSR AirMPNN, R3.
// Sort edges once by dst-bucket (dst>>9, 512 nodes/bucket) with no global
// atomics; payload packed to a single int2 per edge: (src<<9|dloc, eattr).
// Then 3 rounds of fused {LDS aggregate + node MLP} per bucket.
// p[n] = sigmoid(mlp1(xc[n])) is per-NODE (mlp1 depends only on source node).

#define NPB 512        // nodes per bucket
#define NPB_SHIFT 9
#define MAXB 256       // max buckets (N <= 131072)
#define NBLK 640       // histogram/scatter blocks
#define AGG_THREADS 512

__device__ __forceinline__ void load_smem(float* dstp, const float* __restrict__ srcp,
                                          int n, int tid, int nthreads) {
    for (int i = tid; i < n; i += nthreads) dstp[i] = srcp[i];
}

// sigmoid(mlp1(xj)): 9 -> 32 relu -> 32 relu -> 1 sigmoid
__device__ __forceinline__ float mlp1_eval(const float* xj,
    const float* sW1, const float* sb1, const float* sW2, const float* sb2,
    const float* sW3, float sb3)
{
    float h1[32];
#pragma unroll
    for (int j = 0; j < 32; ++j) h1[j] = sb1[j];
#pragma unroll
    for (int i = 0; i < 9; ++i) {
        float v = xj[i];
#pragma unroll
        for (int j = 0; j < 32; ++j) h1[j] = fmaf(v, sW1[i*32+j], h1[j]);
    }
#pragma unroll
    for (int j = 0; j < 32; ++j) h1[j] = fmaxf(h1[j], 0.0f);
    float h2[32];
#pragma unroll
    for (int j = 0; j < 32; ++j) h2[j] = sb2[j];
#pragma unroll
    for (int i = 0; i < 32; ++i) {
        float v = h1[i];
#pragma unroll
        for (int j = 0; j < 32; ++j) h2[j] = fmaf(v, sW2[i*32+j], h2[j]);
    }
    float m = sb3;
#pragma unroll
    for (int i = 0; i < 32; ++i) m = fmaf(fmaxf(h2[i], 0.0f), sW3[i], m);
    return 1.0f / (1.0f + __expf(-m));
}

// p0: p[n] = sigmoid(mlp1(x[n])); optionally zero agg3 (fallback path)
__global__ __launch_bounds__(256) void p0_kernel(
    const float* __restrict__ x,
    const float* __restrict__ W1, const float* __restrict__ b1,
    const float* __restrict__ W2, const float* __restrict__ b2,
    const float* __restrict__ W3, const float* __restrict__ b3,
    float* __restrict__ p, float* __restrict__ agg3, int N)
{
    __shared__ float sW1[288], sb1[32], sW2[1024], sb2[32], sW3[32], sb3s[1];
    int tid = threadIdx.x;
    load_smem(sW1, W1, 288, tid, 256);
    load_smem(sb1, b1, 32, tid, 256);
    load_smem(sW2, W2, 1024, tid, 256);
    load_smem(sb2, b2, 32, tid, 256);
    load_smem(sW3, W3, 32, tid, 256);
    if (tid == 0) sb3s[0] = b3[0];
    __syncthreads();
    int n = blockIdx.x * 256 + tid;
    if (n >= N) return;
    if (agg3) { agg3[n] = 0.0f; agg3[N + n] = 0.0f; agg3[2*(size_t)N + n] = 0.0f; }
    float xj[9];
#pragma unroll
    for (int i = 0; i < 9; ++i) xj[i] = x[(size_t)n*9 + i];
    p[n] = mlp1_eval(xj, sW1, sb1, sW2, sb2, sW3, sb3s[0]);
}

// ---- bucket sort (no global atomics) ----

__global__ __launch_bounds__(256) void hist_kernel(
    const int* __restrict__ dst, uint* __restrict__ hist_g, int E, int chunk, int B)
{
    __shared__ uint hist[MAXB];
    int tid = threadIdx.x;
    for (int i = tid; i < MAXB; i += 256) hist[i] = 0u;
    __syncthreads();
    int start = blockIdx.x * chunk;
    int end = min(E, start + chunk);
    for (int e = start + tid; e < end; e += 256)
        atomicAdd(&hist[((uint)dst[e]) >> NPB_SHIFT], 1u);
    __syncthreads();
    for (int b = tid; b < B; b += 256)
        hist_g[(size_t)b * NBLK + blockIdx.x] = hist[b];
}

// per-bin exclusive scan over the NBLK block-counts; total[bin] = bin sum
__global__ __launch_bounds__(1024) void scanA_kernel(
    uint* __restrict__ hist_g, uint* __restrict__ total)
{
    __shared__ uint s[1024];
    int t = threadIdx.x;
    int b = blockIdx.x;
    uint v = (t < NBLK) ? hist_g[(size_t)b * NBLK + t] : 0u;
    s[t] = v;
    __syncthreads();
    for (int off = 1; off < 1024; off <<= 1) {
        uint xv = (t >= off) ? s[t - off] : 0u;
        __syncthreads();
        s[t] += xv;
        __syncthreads();
    }
    if (t < NBLK) hist_g[(size_t)b * NBLK + t] = s[t] - v;  // exclusive
    if (t == NBLK - 1) total[b] = s[t];
}

// exclusive scan of bin totals -> base[b]; base[B] = E
__global__ __launch_bounds__(1024) void scanB_kernel(
    const uint* __restrict__ total, uint* __restrict__ base, int B)
{
    __shared__ uint s[1024];
    int t = threadIdx.x;
    uint v = (t < B) ? total[t] : 0u;
    s[t] = v;
    __syncthreads();
    for (int off = 1; off < 1024; off <<= 1) {
        uint xv = (t >= off) ? s[t - off] : 0u;
        __syncthreads();
        s[t] += xv;
        __syncthreads();
    }
    if (t < B) base[t] = s[t] - v;
    if (t == B - 1) base[B] = s[t];
}

// scatter edges into bucket-sorted array: ia = ((src<<9)|dloc, eattr bits)
__global__ __launch_bounds__(256) void scatter_sort_kernel(
    const int* __restrict__ dst, const int* __restrict__ src,
    const float* __restrict__ ea, const uint* __restrict__ base,
    const uint* __restrict__ hist_g,
    int2* __restrict__ ia, int E, int chunk, int B)
{
    __shared__ uint cnt[MAXB];
    int tid = threadIdx.x;
    for (int b = tid; b < B; b += 256)
        cnt[b] = base[b] + hist_g[(size_t)b * NBLK + blockIdx.x];
    __syncthreads();
    int start = blockIdx.x * chunk;
    int end = min(E, start + chunk);
    for (int e = start + tid; e < end; e += 256) {
        uint d = (uint)dst[e];
        uint bin = d >> NPB_SHIFT;
        uint pos = atomicAdd(&cnt[bin], 1u);   // LDS atomic (cheap)
        int2 v;
        v.x = (int)(((uint)src[e] << NPB_SHIFT) | (d & (NPB - 1)));
        v.y = __float_as_int(ea[e]);
        ia[pos] = v;
    }
}

// ---- fused aggregate + node MLP per bucket ----
template<bool LAST>
__global__ __launch_bounds__(AGG_THREADS) void aggnode_kernel(
    const float* __restrict__ xin,
    const int2* __restrict__ ia,
    const uint* __restrict__ base, const float* __restrict__ p_in,
    const float* __restrict__ V1, const float* __restrict__ c1,
    const float* __restrict__ V2, const float* __restrict__ c2,
    const float* __restrict__ W1, const float* __restrict__ b1,
    const float* __restrict__ W2, const float* __restrict__ b2,
    const float* __restrict__ W3, const float* __restrict__ b3,
    const float* __restrict__ H1, const float* __restrict__ d1,
    const float* __restrict__ H2, const float* __restrict__ d2,
    float* __restrict__ xout, float* __restrict__ pout,
    float* __restrict__ finalout, int N)
{
    __shared__ float aggl[NPB];
    __shared__ float sV1[160], sc1[16], sV2[128], sc2[8];
    __shared__ float sW1[288], sb1[32], sW2[1024], sb2[32], sW3[32], sbx[1];
    __shared__ float sH1[128], sd1[16], sH2[16], sdx[1];
    int tid = threadIdx.x;
    for (int i = tid; i < NPB; i += AGG_THREADS) aggl[i] = 0.0f;
    load_smem(sV1, V1, 160, tid, AGG_THREADS);
    load_smem(sc1, c1, 16, tid, AGG_THREADS);
    load_smem(sV2, V2, 128, tid, AGG_THREADS);
    load_smem(sc2, c2, 8, tid, AGG_THREADS);
    if (!LAST) {
        load_smem(sW1, W1, 288, tid, AGG_THREADS);
        load_smem(sb1, b1, 32, tid, AGG_THREADS);
        load_smem(sW2, W2, 1024, tid, AGG_THREADS);
        load_smem(sb2, b2, 32, tid, AGG_THREADS);
        load_smem(sW3, W3, 32, tid, AGG_THREADS);
        if (tid == 0) sbx[0] = b3[0];
    } else {
        load_smem(sH1, H1, 128, tid, AGG_THREADS);
        load_smem(sd1, d1, 16, tid, AGG_THREADS);
        load_smem(sH2, H2, 16, tid, AGG_THREADS);
        if (tid == 0) sdx[0] = d2[0];
    }
    __syncthreads();

    int b = blockIdx.x;
    uint e0 = base[b], e1 = base[b + 1];
    for (uint e = e0 + tid; e < e1; e += AGG_THREADS) {
        int2 v = ia[e];
        float pv = p_in[(uint)v.x >> NPB_SHIFT];
        atomicAdd(&aggl[(uint)v.x & (NPB - 1)], pv * __int_as_float(v.y)); // ds_add
    }
    __syncthreads();

    int n = b * NPB + tid;
    if (tid >= NPB || n >= N) return;

    float t[10];
#pragma unroll
    for (int i = 0; i < 9; ++i) t[i] = xin[(size_t)n*9 + i];
    t[9] = aggl[tid];   // (agg - 0)/1

    float u[16];
#pragma unroll
    for (int j = 0; j < 16; ++j) u[j] = sc1[j];
#pragma unroll
    for (int i = 0; i < 10; ++i) {
        float v = t[i];
#pragma unroll
        for (int j = 0; j < 16; ++j) u[j] = fmaf(v, sV1[i*16+j], u[j]);
    }
#pragma unroll
    for (int j = 0; j < 16; ++j) u[j] = fmaxf(u[j], 0.0f);

    float comb[8];
#pragma unroll
    for (int j = 0; j < 8; ++j) comb[j] = sc2[j];
#pragma unroll
    for (int i = 0; i < 16; ++i) {
        float v = u[i];
#pragma unroll
        for (int j = 0; j < 8; ++j) comb[j] = fmaf(v, sV2[i*8+j], comb[j]);
    }
#pragma unroll
    for (int j = 0; j < 8; ++j) comb[j] = fmaxf(comb[j], 0.0f);

    if (!LAST) {
        float xnew[9];
        xnew[0] = t[0];
#pragma unroll
        for (int j = 0; j < 8; ++j) xnew[1+j] = comb[j];
#pragma unroll
        for (int i = 0; i < 9; ++i) xout[(size_t)n*9 + i] = xnew[i];
        pout[n] = mlp1_eval(xnew, sW1, sb1, sW2, sb2, sW3, sbx[0]);
    } else {
        float hh[16];
#pragma unroll
        for (int j = 0; j < 16; ++j) hh[j] = sd1[j];
#pragma unroll
        for (int i = 0; i < 8; ++i) {
            float v = comb[i];
#pragma unroll
            for (int j = 0; j < 16; ++j) hh[j] = fmaf(v, sH1[i*16+j], hh[j]);
        }
        float o = sdx[0];
#pragma unroll
        for (int j = 0; j < 16; ++j) o = fmaf(fmaxf(hh[j], 0.0f), sH2[j], o);
        finalout[n] = 1.0f / (1.0f + __expf(-o));
    }
}

// ---- fallback (atomic path) kernels ----

__global__ __launch_bounds__(256) void scatter_kernel4(
    const float* __restrict__ p, const int* __restrict__ src, const int* __restrict__ dst,
    const float* __restrict__ eattr, float* __restrict__ agg, int E)
{
    int i = (blockIdx.x * 256 + threadIdx.x) * 4;
    if (i + 3 < E) {
        int4   s = *(const int4*)(src + i);
        int4   d = *(const int4*)(dst + i);
        float4 a = *(const float4*)(eattr + i);
        atomicAdd(&agg[d.x], p[s.x] * a.x);
        atomicAdd(&agg[d.y], p[s.y] * a.y);
        atomicAdd(&agg[d.z], p[s.z] * a.z);
        atomicAdd(&agg[d.w], p[s.w] * a.w);
    } else {
        for (; i < E; ++i) atomicAdd(&agg[dst[i]], p[src[i]] * eattr[i]);
    }
}

template<bool LAST>
__global__ __launch_bounds__(256) void node_kernel(
    const float* __restrict__ xin, const float* __restrict__ agg,
    const float* __restrict__ V1, const float* __restrict__ c1,
    const float* __restrict__ V2, const float* __restrict__ c2,
    const float* __restrict__ W1, const float* __restrict__ b1,
    const float* __restrict__ W2, const float* __restrict__ b2,
    const float* __restrict__ W3, const float* __restrict__ b3,
    const float* __restrict__ H1, const float* __restrict__ d1,
    const float* __restrict__ H2, const float* __restrict__ d2,
    float* __restrict__ xout, float* __restrict__ pout,
    float* __restrict__ finalout, int N)
{
    __shared__ float sV1[160], sc1[16], sV2[128], sc2[8];
    __shared__ float sW1[288], sb1[32], sW2[1024], sb2[32], sW3[32], sbx[1];
    __shared__ float sH1[128], sd1[16], sH2[16], sdx[1];
    int tid = threadIdx.x;
    load_smem(sV1, V1, 160, tid, 256);
    load_smem(sc1, c1, 16, tid, 256);
    load_smem(sV2, V2, 128, tid, 256);
    load_smem(sc2, c2, 8, tid, 256);
    if (!LAST) {
        load_smem(sW1, W1, 288, tid, 256);
        load_smem(sb1, b1, 32, tid, 256);
        load_smem(sW2, W2, 1024, tid, 256);
        load_smem(sb2, b2, 32, tid, 256);
        load_smem(sW3, W3, 32, tid, 256);
        if (tid == 0) sbx[0] = b3[0];
    } else {
        load_smem(sH1, H1, 128, tid, 256);
        load_smem(sd1, d1, 16, tid, 256);
        load_smem(sH2, H2, 16, tid, 256);
        if (tid == 0) sdx[0] = d2[0];
    }
    __syncthreads();
    int n = blockIdx.x * 256 + tid;
    if (n >= N) return;

    float t[10];
#pragma unroll
    for (int i = 0; i < 9; ++i) t[i] = xin[(size_t)n*9 + i];
    t[9] = agg[n];

    float u[16];
#pragma unroll
    for (int j = 0; j < 16; ++j) u[j] = sc1[j];
#pragma unroll
    for (int i = 0; i < 10; ++i) {
        float v = t[i];
#pragma unroll
        for (int j = 0; j < 16; ++j) u[j] = fmaf(v, sV1[i*16+j], u[j]);
    }
#pragma unroll
    for (int j = 0; j < 16; ++j) u[j] = fmaxf(u[j], 0.0f);

    float comb[8];
#pragma unroll
    for (int j = 0; j < 8; ++j) comb[j] = sc2[j];
#pragma unroll
    for (int i = 0; i < 16; ++i) {
        float v = u[i];
#pragma unroll
        for (int j = 0; j < 8; ++j) comb[j] = fmaf(v, sV2[i*8+j], comb[j]);
    }
#pragma unroll
    for (int j = 0; j < 8; ++j) comb[j] = fmaxf(comb[j], 0.0f);

    if (!LAST) {
        float xnew[9];
        xnew[0] = t[0];
#pragma unroll
        for (int j = 0; j < 8; ++j) xnew[1+j] = comb[j];
#pragma unroll
        for (int i = 0; i < 9; ++i) xout[(size_t)n*9 + i] = xnew[i];
        pout[n] = mlp1_eval(xnew, sW1, sb1, sW2, sb2, sW3, sbx[0]);
    } else {
        float hh[16];
#pragma unroll
        for (int j = 0; j < 16; ++j) hh[j] = sd1[j];
#pragma unroll
        for (int i = 0; i < 8; ++i) {
            float v = comb[i];
#pragma unroll
            for (int j = 0; j < 16; ++j) hh[j] = fmaf(v, sH1[i*16+j], hh[j]);
        }
        float o = sdx[0];
#pragma unroll
        for (int j = 0; j < 16; ++j) o = fmaf(fmaxf(hh[j], 0.0f), sH2[j], o);
        finalout[n] = 1.0f / (1.0f + __expf(-o));
    }
}

extern "C" void kernel_launch(void* const* d_in, const int* in_sizes, int n_in,
                              void* d_out, int out_size, void* d_ws, size_t ws_size,
                              hipStream_t stream)
{
    const float* x     = (const float*)d_in[0];
    const float* eattr = (const float*)d_in[1];
    const int*   eidx  = (const int*)d_in[2];
    const float *W1=(const float*)d_in[3],  *b1=(const float*)d_in[4];
    const float *W2=(const float*)d_in[5],  *b2=(const float*)d_in[6];
    const float *W3=(const float*)d_in[7],  *b3=(const float*)d_in[8];
    const float *V1=(const float*)d_in[9],  *c1=(const float*)d_in[10];
    const float *V2=(const float*)d_in[11], *c2=(const float*)d_in[12];
    const float *H1=(const float*)d_in[13], *d1=(const float*)d_in[14];
    const float *H2=(const float*)d_in[15], *d2=(const float*)d_in[16];
    int N = in_sizes[0] / 9;
    int E = in_sizes[1];
    const int* src = eidx;
    const int* dst = eidx + E;
    float* out = (float*)d_out;
    int B = (N + NPB - 1) / NPB;

    // main-path workspace
    size_t need = (size_t)E * 8                      // ia
                + (size_t)N * 9 * 4 * 2              // xcA, xcB
                + (size_t)N * 4 * 2                  // pA, pB
                + (size_t)MAXB * NBLK * 4            // hist_g
                + (size_t)MAXB * 4                   // total
                + (size_t)(MAXB + 1) * 4             // base
                + 64;

    dim3 thr(256);
    dim3 blkN((N + 255) / 256);

    // packed field requires src < 2^(32-NPB_SHIFT)
    bool packable = ((long long)N << NPB_SHIFT) < (1LL << 32);

    if (B <= MAXB && packable && ws_size >= need) {
        char* w = (char*)d_ws;
        int2* ia      = (int2*)w;              w += (size_t)E * 8;
        float* xcA    = (float*)w;             w += (size_t)N * 9 * 4;
        float* xcB    = (float*)w;             w += (size_t)N * 9 * 4;
        float* pA     = (float*)w;             w += (size_t)N * 4;
        float* pB     = (float*)w;             w += (size_t)N * 4;
        uint* hist_g  = (uint*)w;              w += (size_t)MAXB * NBLK * 4;
        uint* total   = (uint*)w;              w += (size_t)MAXB * 4;
        uint* base    = (uint*)w;

        int chunk = (E + NBLK - 1) / NBLK;

        p0_kernel<<<blkN, thr, 0, stream>>>(x, W1,b1,W2,b2,W3,b3, pA, nullptr, N);
        hist_kernel<<<dim3(NBLK), thr, 0, stream>>>(dst, hist_g, E, chunk, B);
        scanA_kernel<<<dim3(B), dim3(1024), 0, stream>>>(hist_g, total);
        scanB_kernel<<<dim3(1), dim3(1024), 0, stream>>>(total, base, B);
        scatter_sort_kernel<<<dim3(NBLK), thr, 0, stream>>>(dst, src, eattr, base, hist_g,
                                                            ia, E, chunk, B);
        aggnode_kernel<false><<<dim3(B), dim3(AGG_THREADS), 0, stream>>>(x, ia, base, pA,
            V1,c1,V2,c2, W1,b1,W2,b2,W3,b3, H1,d1,H2,d2, xcA, pB, nullptr, N);
        aggnode_kernel<false><<<dim3(B), dim3(AGG_THREADS), 0, stream>>>(xcA, ia, base, pB,
            V1,c1,V2,c2, W1,b1,W2,b2,W3,b3, H1,d1,H2,d2, xcB, pA, nullptr, N);
        aggnode_kernel<true><<<dim3(B), dim3(AGG_THREADS), 0, stream>>>(xcB, ia, base, pA,
            V1,c1,V2,c2, W1,b1,W2,b2,W3,b3, H1,d1,H2,d2, nullptr, nullptr, out, N);
    } else {
        // fallback: atomic path (ws ~8.8 MB)
        float* ws   = (float*)d_ws;
        float* xcA  = ws;
        float* xcB  = xcA + (size_t)N * 9;
        float* p    = xcB + (size_t)N * 9;
        float* agg3 = p + N;
        dim3 blkE4(((E + 3) / 4 + 255) / 256);

        p0_kernel<<<blkN, thr, 0, stream>>>(x, W1,b1,W2,b2,W3,b3, p, agg3, N);
        scatter_kernel4<<<blkE4, thr, 0, stream>>>(p, src, dst, eattr, agg3, E);
        node_kernel<false><<<blkN, thr, 0, stream>>>(x, agg3, V1,c1,V2,c2, W1,b1,W2,b2,W3,b3,
                                                     H1,d1,H2,d2, xcA, p, nullptr, N);
        scatter_kernel4<<<blkE4, thr, 0, stream>>>(p, src, dst, eattr, agg3 + N, E);
        node_kernel<false><<<blkN, thr, 0, stream>>>(xcA, agg3 + N, V1,c1,V2,c2, W1,b1,W2,b2,W3,b3,
                                                     H1,d1,H2,d2, xcB, p, nullptr, N);
        scatter_kernel4<<<blkE4, thr, 0, stream>>>(p, src, dst, eattr, agg3 + 2*(size_t)N, E);
        node_kernel<true><<<blkN, thr, 0, stream>>>(xcB, agg3 + 2*(size_t)N, V1,c1,V2,c2,
                                                    W1,b1,W2,b2,W3,b3, H1,d1,H2,d2,
                                                    nullptr, nullptr, out, N);
    }
}